// Round 1
// baseline (1074.256 us; speedup 1.0000x reference)
//
#include <hip/hip_runtime.h>
#include <math.h>

#define LSEQ 2048
#define NB   32
#define DM   256
#define ED   100
#define BL   256   // row tile (l dimension)
#define BC   128   // col tile (c dimension)
#define STS  260   // sT LDS stride (256+4, keeps 16B align)
#define CTS  132   // ceT LDS stride (128+4)

typedef float f4 __attribute__((ext_vector_type(4)));

// ---- staging helpers -------------------------------------------------------

// stage 256 rows x 100 cols of s (row-major, contiguous rows) transposed into sT[k][row]
__device__ __forceinline__ void stage_sT(float* sT, const float* __restrict__ sp0, int tid) {
#pragma unroll
  for (int i = 0; i < 25; ++i) {            // 25*256 = 6400 float4
    int idx = tid + 256 * i;
    int row = idx / 25, q = idx - row * 25;
    f4 v = *(const f4*)(sp0 + row * ED + q * 4);
    float* dst = sT + (q * 4) * STS + row;
    dst[0] = v[0]; dst[STS] = v[1]; dst[2 * STS] = v[2]; dst[3 * STS] = v[3];
  }
}

// stage 128 rows (categories) x 100 cols of ce transposed into ceT[k][c], zero-pad c>=C
__device__ __forceinline__ void stage_ceT(float* ceT, const float* __restrict__ ce,
                                          int c0, int C, int tid) {
#pragma unroll
  for (int i = 0; i < 13; ++i) {            // 13*256 >= 3200
    int idx = tid + 256 * i;
    if (idx < 3200) {
      int row = idx / 25, q = idx - row * 25;
      int c = c0 + row;
      f4 v = {0.f, 0.f, 0.f, 0.f};
      if (c < C) v = *(const f4*)(ce + c * ED + q * 4);
      float* dst = ceT + (q * 4) * CTS + row;
      dst[0] = v[0]; dst[CTS] = v[1]; dst[2 * CTS] = v[2]; dst[3 * CTS] = v[3];
    }
  }
}

// ---- text_mean -------------------------------------------------------------

__global__ __launch_bounds__(256) void tm_partial_k(const float* __restrict__ x,
                                                    float* __restrict__ tp) {
  int lc = blockIdx.x, b = blockIdx.y, d = threadIdx.x;
  const float* xp = x + ((long)b * LSEQ + lc * 128) * DM + d;
  float a = 0.f;
#pragma unroll 8
  for (int i = 0; i < 128; ++i) a += xp[(long)i * DM];
  tp[((long)lc * NB + b) * DM + d] = a;
}

__global__ __launch_bounds__(256) void tm_reduce_k(const float* __restrict__ tp,
                                                   float* __restrict__ tm) {
  int idx = blockIdx.x * 256 + threadIdx.x;   // < 8192
  int b = idx >> 8, d = idx & 255;
  float a = 0.f;
#pragma unroll
  for (int lc = 0; lc < 16; ++lc) a += tp[((long)lc * NB + b) * DM + d];
  tm[idx] = a * (1.f / LSEQ);
}

// ---- s = tanh(prev * (x @ aw)) --------------------------------------------
// grid: 256 blocks (row tiles of 256), 256 threads, micro 16x8, K=256 in 4 chunks of 64

__global__ __launch_bounds__(256) void s_kernel(const float* __restrict__ x,
                                                const float* __restrict__ aw,
                                                const float* __restrict__ prevb,
                                                float* __restrict__ s, int hasPrev) {
  __shared__ float xT[64 * STS];    // [k][row]
  __shared__ float awS[64 * CTS];   // [k][e], e zero-padded 100..127
  __shared__ float psL[BL];
  const int tid = threadIdx.x;
  const int rg = tid >> 4, cg = tid & 15;
  const int r16 = rg * 16, c8 = cg * 8;
  const long rt0 = (long)blockIdx.x * BL;

  if (hasPrev) psL[tid] = prevb[rt0 + tid];

  float acc[16][8];
#pragma unroll
  for (int i = 0; i < 16; ++i)
#pragma unroll
    for (int j = 0; j < 8; ++j) acc[i][j] = 0.f;

  for (int kc = 0; kc < 4; ++kc) {
    __syncthreads();
    // stage xT (transpose 256 rows x 64 k)
    {
      const float* xp = x + rt0 * DM + kc * 64;
#pragma unroll
      for (int i = 0; i < 16; ++i) {          // 16*256 = 4096 float4
        int idx = tid + 256 * i;
        int row = idx >> 4, q = idx & 15;
        f4 v = *(const f4*)(xp + (long)row * DM + q * 4);
        float* dst = xT + (q * 4) * STS + row;
        dst[0] = v[0]; dst[STS] = v[1]; dst[2 * STS] = v[2]; dst[3 * STS] = v[3];
      }
    }
    // stage awS rows k=kc*64..+63, cols e<100 (+zero pad)
    for (int idx = tid; idx < 1600; idx += 256) {  // 64*25 float4
      int kk = idx / 25, q = idx - kk * 25;
      f4 v = *(const f4*)(aw + (long)(kc * 64 + kk) * ED + q * 4);
      *(f4*)(awS + kk * CTS + q * 4) = v;
    }
    for (int idx = tid; idx < 1792; idx += 256) {  // 64*28 zeros
      int kk = idx / 28, e = 100 + (idx - kk * 28);
      awS[kk * CTS + e] = 0.f;
    }
    __syncthreads();

    for (int kk = 0; kk < 64; ++kk) {
      const float* ap = xT + kk * STS + r16;
      const float* bp = awS + kk * CTS + c8;
      f4 A0 = *(const f4*)ap, A1 = *(const f4*)(ap + 4), A2 = *(const f4*)(ap + 8), A3 = *(const f4*)(ap + 12);
      f4 B0 = *(const f4*)bp, B1 = *(const f4*)(bp + 4);
      float a_[16] = {A0[0],A0[1],A0[2],A0[3],A1[0],A1[1],A1[2],A1[3],
                      A2[0],A2[1],A2[2],A2[3],A3[0],A3[1],A3[2],A3[3]};
      float b_[8]  = {B0[0],B0[1],B0[2],B0[3],B1[0],B1[1],B1[2],B1[3]};
#pragma unroll
      for (int i = 0; i < 16; ++i)
#pragma unroll
        for (int j = 0; j < 8; ++j) acc[i][j] = fmaf(a_[i], b_[j], acc[i][j]);
    }
  }

  // epilogue: tanh(scale*acc) -> s[r][e], e<100
#pragma unroll
  for (int i = 0; i < 16; ++i) {
    long r = rt0 + r16 + i;
    float sc = hasPrev ? psL[r16 + i] : 1.f;
    float o[8];
#pragma unroll
    for (int j = 0; j < 8; ++j) o[j] = tanhf(sc * acc[i][j]);
    float* sp = s + r * ED + c8;
    if (cg < 12) {
      *(f4*)sp = (f4){o[0], o[1], o[2], o[3]};
      *(f4*)(sp + 4) = (f4){o[4], o[5], o[6], o[7]};
    } else if (cg == 12) {
      *(f4*)sp = (f4){o[0], o[1], o[2], o[3]};
    }
  }
}

// ---- sweep 1: Z partials (column sums of exp(score)) ----------------------
// grid: dim3(nct, NL, NB); block loops over ltiles row-tiles of its chunk.

__global__ __launch_bounds__(256) void sweep_col(const float* __restrict__ s,
                                                 const float* __restrict__ ce,
                                                 float* __restrict__ partial,
                                                 int C, int ltiles) {
  __shared__ float sT[ED * STS];
  __shared__ float ceT[ED * CTS];
  const int tid = threadIdx.x;
  const int rg = tid >> 4, cg = tid & 15;
  const int r16 = rg * 16, c8 = cg * 8;
  const int b = blockIdx.z, c0 = blockIdx.x * BC, nchunk = blockIdx.y;
  const long lbase = (long)b * LSEQ + (long)nchunk * ltiles * BL;

  stage_ceT(ceT, ce, c0, C, tid);

  float colacc[8];
#pragma unroll
  for (int j = 0; j < 8; ++j) colacc[j] = 0.f;

  for (int lt = 0; lt < ltiles; ++lt) {
    __syncthreads();
    stage_sT(sT, s + (lbase + (long)lt * BL) * ED, tid);
    __syncthreads();

    float acc[16][8];
#pragma unroll
    for (int i = 0; i < 16; ++i)
#pragma unroll
      for (int j = 0; j < 8; ++j) acc[i][j] = 0.f;

    for (int k = 0; k < ED; ++k) {
      const float* ap = sT + k * STS + r16;
      const float* bp = ceT + k * CTS + c8;
      f4 A0 = *(const f4*)ap, A1 = *(const f4*)(ap + 4), A2 = *(const f4*)(ap + 8), A3 = *(const f4*)(ap + 12);
      f4 B0 = *(const f4*)bp, B1 = *(const f4*)(bp + 4);
      float a_[16] = {A0[0],A0[1],A0[2],A0[3],A1[0],A1[1],A1[2],A1[3],
                      A2[0],A2[1],A2[2],A2[3],A3[0],A3[1],A3[2],A3[3]};
      float b_[8]  = {B0[0],B0[1],B0[2],B0[3],B1[0],B1[1],B1[2],B1[3]};
#pragma unroll
      for (int i = 0; i < 16; ++i)
#pragma unroll
        for (int j = 0; j < 8; ++j) acc[i][j] = fmaf(a_[i], b_[j], acc[i][j]);
    }
#pragma unroll
    for (int i = 0; i < 16; ++i)
#pragma unroll
      for (int j = 0; j < 8; ++j) colacc[j] += __expf(acc[i][j]);
  }

  __syncthreads();
  float* red = sT;  // reuse as [16][BC]
#pragma unroll
  for (int j = 0; j < 8; ++j) red[rg * BC + c8 + j] = colacc[j];
  __syncthreads();
  if (tid < BC) {
    float z = 0.f;
#pragma unroll
    for (int g = 0; g < 16; ++g) z += red[g * BC + tid];
    partial[((long)nchunk * NB + b) * 1024 + c0 + tid] = z;
  }
}

// ---- Z reduce + w2 = 1/(C*Z) ----------------------------------------------

__global__ __launch_bounds__(256) void wz_kernel(const float* __restrict__ partial,
                                                 float* __restrict__ Z,
                                                 float* __restrict__ w, int NL, int C) {
  int idx = blockIdx.x * 256 + threadIdx.x;  // < 32768
  int b = idx >> 10, c = idx & 1023;
  float z = 0.f;
  for (int n = 0; n < NL; ++n) z += partial[((long)n * NB + b) * 1024 + c];
  Z[idx] = z;
  w[idx] = (c < C) ? 1.f / ((float)C * z) : 0.f;
}

// ---- sweep 2/3: row sums of exp(score)*w[c], optional per-row scale -------
// grid: dim3(8, NB) (l-tiles of 256); block loops all c-tiles.

__global__ __launch_bounds__(256) void sweep_row(const float* __restrict__ s,
                                                 const float* __restrict__ ce,
                                                 const float* __restrict__ w,
                                                 const float* __restrict__ ps,
                                                 float* __restrict__ out,
                                                 int C, int nct) {
  __shared__ float sT[ED * STS];
  __shared__ float ceT[ED * CTS];
  __shared__ float wS[BC];
  const int tid = threadIdx.x;
  const int rg = tid >> 4, cg = tid & 15;
  const int r16 = rg * 16, c8 = cg * 8;
  const int b = blockIdx.y;
  const long lbase = (long)b * LSEQ + (long)blockIdx.x * BL;

  stage_sT(sT, s + lbase * ED, tid);

  float rowacc[16];
#pragma unroll
  for (int i = 0; i < 16; ++i) rowacc[i] = 0.f;

  for (int ct = 0; ct < nct; ++ct) {
    int c0 = ct * BC;
    __syncthreads();
    stage_ceT(ceT, ce, c0, C, tid);
    if (tid < 32) *(f4*)(wS + tid * 4) = *(const f4*)(w + b * 1024 + c0 + tid * 4);
    __syncthreads();

    float acc[16][8];
#pragma unroll
    for (int i = 0; i < 16; ++i)
#pragma unroll
      for (int j = 0; j < 8; ++j) acc[i][j] = 0.f;

    for (int k = 0; k < ED; ++k) {
      const float* ap = sT + k * STS + r16;
      const float* bp = ceT + k * CTS + c8;
      f4 A0 = *(const f4*)ap, A1 = *(const f4*)(ap + 4), A2 = *(const f4*)(ap + 8), A3 = *(const f4*)(ap + 12);
      f4 B0 = *(const f4*)bp, B1 = *(const f4*)(bp + 4);
      float a_[16] = {A0[0],A0[1],A0[2],A0[3],A1[0],A1[1],A1[2],A1[3],
                      A2[0],A2[1],A2[2],A2[3],A3[0],A3[1],A3[2],A3[3]};
      float b_[8]  = {B0[0],B0[1],B0[2],B0[3],B1[0],B1[1],B1[2],B1[3]};
#pragma unroll
      for (int i = 0; i < 16; ++i)
#pragma unroll
        for (int j = 0; j < 8; ++j) acc[i][j] = fmaf(a_[i], b_[j], acc[i][j]);
    }
#pragma unroll
    for (int j = 0; j < 8; ++j) {
      float wj = wS[c8 + j];
#pragma unroll
      for (int i = 0; i < 16; ++i) rowacc[i] = fmaf(__expf(acc[i][j]), wj, rowacc[i]);
    }
  }

  __syncthreads();
  float* red = sT;  // reuse as [16][BL]
#pragma unroll
  for (int i = 0; i < 16; ++i) red[cg * BL + r16 + i] = rowacc[i];
  __syncthreads();
  {
    float v = 0.f;
#pragma unroll
    for (int g = 0; g < 16; ++g) v += red[g * BL + tid];
    if (ps) v *= ps[lbase + tid];
    out[lbase + tid] = v;
  }
}

// ---- pooled = sum_l gs[b,l]*x[b,l,:]  (gs already includes prev & 1/C) ----

__global__ __launch_bounds__(256) void pooled_partial_k(const float* __restrict__ x,
                                                        const float* __restrict__ gs,
                                                        float* __restrict__ pp) {
  int lc = blockIdx.x, b = blockIdx.y, d = threadIdx.x;
  const float* xp = x + ((long)b * LSEQ + lc * 256) * DM + d;
  const float* gp = gs + (long)b * LSEQ + lc * 256;
  float a = 0.f;
#pragma unroll 8
  for (int i = 0; i < 256; ++i) a = fmaf(gp[i], xp[(long)i * DM], a);
  pp[((long)lc * NB + b) * DM + d] = a;
}

__global__ __launch_bounds__(256) void pooled_reduce_k(const float* __restrict__ pp,
                                                       float* __restrict__ pooled) {
  int idx = blockIdx.x * 256 + threadIdx.x;  // < 8192
  int b = idx >> 8, d = idx & 255;
  float a = 0.f;
#pragma unroll
  for (int lc = 0; lc < 8; ++lc) a += pp[((long)lc * NB + b) * DM + d];
  pooled[idx] = a;
}

// ---- dense = relu([tm, pooled] @ dw + db) ---------------------------------

__global__ __launch_bounds__(256) void dense_k(const float* __restrict__ tm,
                                               const float* __restrict__ pooled,
                                               const float* __restrict__ dw,
                                               const float* __restrict__ db,
                                               float* __restrict__ dense) {
  __shared__ float f[2 * DM];
  int b = blockIdx.x, t = threadIdx.x;
  f[t] = tm[b * DM + t];
  f[DM + t] = pooled[b * DM + t];
  __syncthreads();
  float a = db[t];
#pragma unroll 8
  for (int k = 0; k < 2 * DM; ++k) a = fmaf(f[k], dw[(long)k * DM + t], a);
  dense[b * DM + t] = fmaxf(a, 0.f);
}

// ---- logits = dense @ pw + pb ---------------------------------------------

__global__ __launch_bounds__(256) void logits_k(const float* __restrict__ dense,
                                                const float* __restrict__ pw,
                                                const float* __restrict__ pb,
                                                float* __restrict__ logits, int C) {
  __shared__ float dS[DM];
  int b = blockIdx.y, t = threadIdx.x;
  int c = blockIdx.x * 256 + t;
  dS[t] = dense[b * DM + t];
  __syncthreads();
  if (c < C) {
    float a = pb[c];
#pragma unroll 8
    for (int k = 0; k < DM; ++k) a = fmaf(dS[k], pw[(long)k * C + c], a);
    logits[b * 1024 + c] = a;
  }
}

// ---- softmax over C, write pred to d_out, optionally w3 = pred/(C*Z) ------

__global__ __launch_bounds__(256) void softmax_k(const float* __restrict__ logits,
                                                 const float* __restrict__ Z,
                                                 float* __restrict__ out,
                                                 float* __restrict__ w,
                                                 int C, int writeW) {
  __shared__ float buf[1024];
  __shared__ float red[256];
  int b = blockIdx.x, t = threadIdx.x;
  float m = -1e30f;
  for (int c = t; c < C; c += 256) {
    float v = logits[b * 1024 + c];
    buf[c] = v;
    m = fmaxf(m, v);
  }
  red[t] = m;
  __syncthreads();
  for (int s2 = 128; s2 > 0; s2 >>= 1) {
    if (t < s2) red[t] = fmaxf(red[t], red[t + s2]);
    __syncthreads();
  }
  m = red[0];
  __syncthreads();
  float sum = 0.f;
  for (int c = t; c < C; c += 256) {
    float e = __expf(buf[c] - m);
    buf[c] = e;
    sum += e;
  }
  red[t] = sum;
  __syncthreads();
  for (int s2 = 128; s2 > 0; s2 >>= 1) {
    if (t < s2) red[t] += red[t + s2];
    __syncthreads();
  }
  float inv = 1.f / red[0];
  for (int c = t; c < C; c += 256) out[(long)b * C + c] = buf[c] * inv;
  if (writeW) {
    float invC = 1.f / (float)C;
    for (int c = t; c < 1024; c += 256)
      w[b * 1024 + c] = (c < C) ? (buf[c] * inv) * invC / Z[b * 1024 + c] : 0.f;
  }
}

// ---- host -----------------------------------------------------------------

extern "C" void kernel_launch(void* const* d_in, const int* in_sizes, int n_in,
                              void* d_out, int out_size, void* d_ws, size_t ws_size,
                              hipStream_t stream) {
  (void)in_sizes; (void)n_in; (void)out_size; (void)ws_size;
  const float* x = (const float*)d_in[0];

  const int Cs[3]     = {21, 191, 1009};
  const int ncts[3]   = {1, 2, 8};     // ceil(C/128)
  const int NLs[3]    = {8, 4, 1};     // l-chunks for sweep_col (grid fill)
  const int outoff[3] = {0, 672, 6784};

  float* ws = (float*)d_ws;
  float* s      = ws; ws += 6553600;        // [R][100]
  float* part   = ws; ws += 8 * 32 * 1024;  // Z partials [NL][B][1024]
  float* Zb     = ws; ws += 32768;          // [B][1024]
  float* wb     = ws; ws += 32768;          // [B][1024]
  float* gs     = ws; ws += 65536;          // [B][L]
  float* prevb  = ws; ws += 65536;          // [B][L]
  float* tp     = ws; ws += 131072;         // tm partials [16][B][256]
  float* tm     = ws; ws += 8192;           // [B][256]
  float* pp     = ws; ws += 65536;          // pooled partials [8][B][256]
  float* pooled = ws; ws += 8192;           // [B][256]
  float* dense  = ws; ws += 8192;           // [B][256]
  float* logits = ws; ws += 32768;          // [B][1024]

  tm_partial_k<<<dim3(16, NB), 256, 0, stream>>>(x, tp);
  tm_reduce_k<<<32, 256, 0, stream>>>(tp, tm);

  for (int h = 0; h < 3; ++h) {
    const float* ce = (const float*)d_in[1 + 6 * h + 0];
    const float* aw = (const float*)d_in[1 + 6 * h + 1];
    const float* dw = (const float*)d_in[1 + 6 * h + 2];
    const float* db = (const float*)d_in[1 + 6 * h + 3];
    const float* pw = (const float*)d_in[1 + 6 * h + 4];
    const float* pb = (const float*)d_in[1 + 6 * h + 5];
    const int C = Cs[h], nct = ncts[h], NL = NLs[h];
    const int ltiles = (LSEQ / NL) / BL;  // 1, 2, 8

    s_kernel<<<256, 256, 0, stream>>>(x, aw, prevb, s, h > 0 ? 1 : 0);
    sweep_col<<<dim3(nct, NL, NB), 256, 0, stream>>>(s, ce, part, C, ltiles);
    wz_kernel<<<128, 256, 0, stream>>>(part, Zb, wb, NL, C);
    sweep_row<<<dim3(8, NB), 256, 0, stream>>>(s, ce, wb, h > 0 ? prevb : nullptr, gs, C, nct);
    pooled_partial_k<<<dim3(8, NB), 256, 0, stream>>>(x, gs, pp);
    pooled_reduce_k<<<32, 256, 0, stream>>>(pp, pooled);
    dense_k<<<NB, 256, 0, stream>>>(tm, pooled, dw, db, dense);
    logits_k<<<dim3((C + 255) / 256, NB), 256, 0, stream>>>(dense, pw, pb, logits, C);
    softmax_k<<<NB, 256, 0, stream>>>(logits, Zb, (float*)d_out + outoff[h], wb, C, h < 2 ? 1 : 0);
    if (h < 2)
      sweep_row<<<dim3(8, NB), 256, 0, stream>>>(s, ce, wb, nullptr, prevb, C, nct);
  }
}

// Round 2
// 909.369 us; speedup vs baseline: 1.1813x; 1.1813x over previous
//
#include <hip/hip_runtime.h>
#include <math.h>

#define LSEQ 2048
#define NB   32
#define DM   256
#define ED   100
#define RT   65536   // total rows B*L
#define BL   256     // sweep row tile
#define KC   25      // sweep k-chunk
#define STS  260     // sS stride
#define CTS  132     // ceS stride
#define BLX  128     // s_kernel row tile

typedef float f4 __attribute__((ext_vector_type(4)));

// ---- text_mean -------------------------------------------------------------

__global__ __launch_bounds__(256) void tm_partial_k(const float* __restrict__ x,
                                                    float* __restrict__ tp) {
  int lc = blockIdx.x, b = blockIdx.y, d = threadIdx.x;
  const float* xp = x + ((long)b * LSEQ + lc * 128) * DM + d;
  float a = 0.f;
#pragma unroll 8
  for (int i = 0; i < 128; ++i) a += xp[(long)i * DM];
  tp[((long)lc * NB + b) * DM + d] = a;
}

__global__ __launch_bounds__(256) void tm_reduce_k(const float* __restrict__ tp,
                                                   float* __restrict__ tm) {
  int idx = blockIdx.x * 256 + threadIdx.x;   // < 8192
  int b = idx >> 8, d = idx & 255;
  float a = 0.f;
#pragma unroll
  for (int lc = 0; lc < 16; ++lc) a += tp[((long)lc * NB + b) * DM + d];
  tm[idx] = a * (1.f / LSEQ);
}

// ---- ce transpose: ceG[k][1024] zero-padded -------------------------------

__global__ __launch_bounds__(256) void cet_k(const float* __restrict__ ce,
                                             float* __restrict__ ceG, int C) {
  int idx = blockIdx.x * 256 + threadIdx.x;   // < 102400
  int k = idx >> 10, c = idx & 1023;
  ceG[idx] = (c < C) ? ce[c * ED + k] : 0.f;
}

// ---- s_kernel: sG[k][row] = tanh(prev[row] * (x @ aw))[row][k] ------------
// grid 512 (row tiles of 128), 256 thr, micro 8x8, K=256 in 8 chunks of 32

__global__ __launch_bounds__(256) void s_kernel(const float* __restrict__ x,
                                                const float* __restrict__ aw,
                                                const float* __restrict__ prevb,
                                                float* __restrict__ sG, int hasPrev) {
  __shared__ float xT[32 * 132];   // [k][row]
  __shared__ float awS[32 * 132];  // [k][e] padded 100..127
  __shared__ float psL[BLX];
  const int tid = threadIdx.x;
  const int rg = tid >> 4, cg = tid & 15;
  const int r8 = rg * 8, c8 = cg * 8;
  const long rt0 = (long)blockIdx.x * BLX;

  if (hasPrev && tid < BLX) psL[tid] = prevb[rt0 + tid];

  float acc[8][8];
#pragma unroll
  for (int i = 0; i < 8; ++i)
#pragma unroll
    for (int j = 0; j < 8; ++j) acc[i][j] = 0.f;

#pragma unroll 1
  for (int kc = 0; kc < 8; ++kc) {
    __syncthreads();
    // stage xT: transpose 128 rows x 32 k
#pragma unroll
    for (int i = 0; i < 4; ++i) {            // 1024 f4
      int idx = tid + 256 * i;
      int row = idx >> 3, q = idx & 7;
      f4 v = *(const f4*)(x + (rt0 + row) * DM + kc * 32 + q * 4);
      float* dst = xT + (q * 4) * 132 + row;
      dst[0] = v[0]; dst[132] = v[1]; dst[264] = v[2]; dst[396] = v[3];
    }
    // stage awS (row-major already [k][e])
    for (int idx = tid; idx < 800; idx += 256) {   // 32*25 f4
      int kk = idx / 25, q = idx - kk * 25;
      *(f4*)(awS + kk * 132 + q * 4) = *(const f4*)(aw + (long)(kc * 32 + kk) * ED + q * 4);
    }
    for (int idx = tid; idx < 896; idx += 256) {   // 32*28 zeros
      int kk = idx / 28, e = 100 + (idx - kk * 28);
      awS[kk * 132 + e] = 0.f;
    }
    __syncthreads();

    for (int kk = 0; kk < 32; ++kk) {
      const float* ap = xT + kk * 132 + r8;
      const float* bp = awS + kk * 132 + c8;
      f4 A0 = *(const f4*)ap, A1 = *(const f4*)(ap + 4);
      f4 B0 = *(const f4*)bp, B1 = *(const f4*)(bp + 4);
      float a_[8] = {A0[0],A0[1],A0[2],A0[3],A1[0],A1[1],A1[2],A1[3]};
      float b_[8] = {B0[0],B0[1],B0[2],B0[3],B1[0],B1[1],B1[2],B1[3]};
#pragma unroll
      for (int i = 0; i < 8; ++i)
#pragma unroll
        for (int j = 0; j < 8; ++j) acc[i][j] = fmaf(a_[i], b_[j], acc[i][j]);
    }
  }

  // epilogue: write transposed sG[e][row]
#pragma unroll
  for (int j = 0; j < 8; ++j) {
    int e = c8 + j;
    if (e < ED) {
      float o[8];
#pragma unroll
      for (int i = 0; i < 8; ++i) {
        float sc = hasPrev ? psL[r8 + i] : 1.f;
        o[i] = tanhf(sc * acc[i][j]);
      }
      float* sp = sG + (long)e * RT + rt0 + r8;
      *(f4*)sp = (f4){o[0], o[1], o[2], o[3]};
      *(f4*)(sp + 4) = (f4){o[4], o[5], o[6], o[7]};
    }
  }
}

// ---- staging helpers (coalesced, no transpose) ----------------------------

__device__ __forceinline__ void stage_sS(float* sS, const float* __restrict__ src, int tid) {
#pragma unroll
  for (int i = 0; i < 7; ++i) {              // 25*64 = 1600 f4
    int idx = tid + 256 * i;
    if (idx < 1600) {
      int kk = idx >> 6, q = idx & 63;
      *(f4*)(sS + kk * STS + q * 4) = *(const f4*)(src + (long)kk * RT + q * 4);
    }
  }
}

__device__ __forceinline__ void stage_ceS(float* ceS, const float* __restrict__ src, int tid) {
#pragma unroll
  for (int i = 0; i < 4; ++i) {              // 25*32 = 800 f4
    int idx = tid + 256 * i;
    if (idx < 800) {
      int kk = idx >> 5, q = idx & 31;
      *(f4*)(ceS + kk * CTS + q * 4) = *(const f4*)(src + (long)kk * 1024 + q * 4);
    }
  }
}

// ---- sweep_col: Z partials. grid (nct, 8, NB) -----------------------------

__global__ __launch_bounds__(256) void sweep_col(const float* __restrict__ sG,
                                                 const float* __restrict__ ceG,
                                                 float* __restrict__ partial) {
  __shared__ float sS[KC * STS];
  __shared__ float ceS[KC * CTS];
  const int tid = threadIdx.x;
  const int rg = tid >> 4, cg = tid & 15;
  const int r16 = rg * 16, c8 = cg * 8;
  const int c0 = blockIdx.x * 128, lchunk = blockIdx.y, b = blockIdx.z;
  const long lbase = (long)b * LSEQ + lchunk * BL;

  float acc[16][8];
#pragma unroll
  for (int i = 0; i < 16; ++i)
#pragma unroll
    for (int j = 0; j < 8; ++j) acc[i][j] = 0.f;

#pragma unroll 1
  for (int kc = 0; kc < 4; ++kc) {
    __syncthreads();
    stage_sS(sS, sG + (long)(kc * KC) * RT + lbase, tid);
    stage_ceS(ceS, ceG + (long)(kc * KC) * 1024 + c0, tid);
    __syncthreads();
    for (int kk = 0; kk < KC; ++kk) {
      const float* ap = sS + kk * STS + r16;
      const float* bp = ceS + kk * CTS + c8;
      f4 A0 = *(const f4*)ap, A1 = *(const f4*)(ap + 4), A2 = *(const f4*)(ap + 8), A3 = *(const f4*)(ap + 12);
      f4 B0 = *(const f4*)bp, B1 = *(const f4*)(bp + 4);
      float a_[16] = {A0[0],A0[1],A0[2],A0[3],A1[0],A1[1],A1[2],A1[3],
                      A2[0],A2[1],A2[2],A2[3],A3[0],A3[1],A3[2],A3[3]};
      float b_[8]  = {B0[0],B0[1],B0[2],B0[3],B1[0],B1[1],B1[2],B1[3]};
#pragma unroll
      for (int i = 0; i < 16; ++i)
#pragma unroll
        for (int j = 0; j < 8; ++j) acc[i][j] = fmaf(a_[i], b_[j], acc[i][j]);
    }
  }

  float colacc[8];
#pragma unroll
  for (int j = 0; j < 8; ++j) colacc[j] = 0.f;
#pragma unroll
  for (int i = 0; i < 16; ++i)
#pragma unroll
    for (int j = 0; j < 8; ++j) colacc[j] += __expf(acc[i][j]);

  __syncthreads();
  float* red = sS;  // [16][128]
#pragma unroll
  for (int j = 0; j < 8; ++j) red[rg * 128 + c8 + j] = colacc[j];
  __syncthreads();
  if (tid < 128) {
    float z = 0.f;
#pragma unroll
    for (int g = 0; g < 16; ++g) z += red[g * 128 + tid];
    partial[((long)lchunk * NB + b) * 1024 + c0 + tid] = z;
  }
}

// ---- Z reduce + w2 = 1/(C*Z) ----------------------------------------------

__global__ __launch_bounds__(256) void wz_kernel(const float* __restrict__ partial,
                                                 float* __restrict__ Z,
                                                 float* __restrict__ w, int C) {
  int idx = blockIdx.x * 256 + threadIdx.x;  // < 32768
  int b = idx >> 10, c = idx & 1023;
  float z = 0.f;
#pragma unroll
  for (int n = 0; n < 8; ++n) z += partial[((long)n * NB + b) * 1024 + c];
  Z[idx] = z;
  w[idx] = (c < C) ? 1.f / ((float)C * z) : 0.f;
}

// ---- sweep_row: partial row sums. grid (8, NB, nct) -----------------------

__global__ __launch_bounds__(256) void sweep_row(const float* __restrict__ sG,
                                                 const float* __restrict__ ceG,
                                                 const float* __restrict__ w,
                                                 float* __restrict__ rowp) {
  __shared__ float sS[KC * STS];
  __shared__ float ceS[KC * CTS];
  __shared__ float wS[128];
  const int tid = threadIdx.x;
  const int rg = tid >> 4, cg = tid & 15;
  const int r16 = rg * 16, c8 = cg * 8;
  const int lt = blockIdx.x, b = blockIdx.y, ct = blockIdx.z;
  const int c0 = ct * 128;
  const long lbase = (long)b * LSEQ + lt * BL;

  if (tid < 32) *(f4*)(wS + tid * 4) = *(const f4*)(w + b * 1024 + c0 + tid * 4);

  float acc[16][8];
#pragma unroll
  for (int i = 0; i < 16; ++i)
#pragma unroll
    for (int j = 0; j < 8; ++j) acc[i][j] = 0.f;

#pragma unroll 1
  for (int kc = 0; kc < 4; ++kc) {
    __syncthreads();
    stage_sS(sS, sG + (long)(kc * KC) * RT + lbase, tid);
    stage_ceS(ceS, ceG + (long)(kc * KC) * 1024 + c0, tid);
    __syncthreads();
    for (int kk = 0; kk < KC; ++kk) {
      const float* ap = sS + kk * STS + r16;
      const float* bp = ceS + kk * CTS + c8;
      f4 A0 = *(const f4*)ap, A1 = *(const f4*)(ap + 4), A2 = *(const f4*)(ap + 8), A3 = *(const f4*)(ap + 12);
      f4 B0 = *(const f4*)bp, B1 = *(const f4*)(bp + 4);
      float a_[16] = {A0[0],A0[1],A0[2],A0[3],A1[0],A1[1],A1[2],A1[3],
                      A2[0],A2[1],A2[2],A2[3],A3[0],A3[1],A3[2],A3[3]};
      float b_[8]  = {B0[0],B0[1],B0[2],B0[3],B1[0],B1[1],B1[2],B1[3]};
#pragma unroll
      for (int i = 0; i < 16; ++i)
#pragma unroll
        for (int j = 0; j < 8; ++j) acc[i][j] = fmaf(a_[i], b_[j], acc[i][j]);
    }
  }

  float rowacc[16];
#pragma unroll
  for (int i = 0; i < 16; ++i) rowacc[i] = 0.f;
#pragma unroll
  for (int j = 0; j < 8; ++j) {
    float wj = wS[c8 + j];
#pragma unroll
    for (int i = 0; i < 16; ++i) rowacc[i] = fmaf(__expf(acc[i][j]), wj, rowacc[i]);
  }

  __syncthreads();
  float* red = sS;  // [16][256]
#pragma unroll
  for (int i = 0; i < 16; ++i) red[cg * 256 + r16 + i] = rowacc[i];
  __syncthreads();
  {
    float v = 0.f;
#pragma unroll
    for (int g = 0; g < 16; ++g) v += red[g * 256 + tid];
    rowp[(long)ct * RT + lbase + tid] = v;
  }
}

// ---- rowp reduce over ct (+ optional per-row scale) -----------------------

__global__ __launch_bounds__(256) void rowred_k(const float* __restrict__ rowp,
                                                const float* __restrict__ ps,
                                                float* __restrict__ out, int nct) {
  int idx = blockIdx.x * 256 + threadIdx.x;  // < 65536
  float v = 0.f;
  for (int ct = 0; ct < nct; ++ct) v += rowp[(long)ct * RT + idx];
  if (ps) v *= ps[idx];
  out[idx] = v;
}

// ---- pooled = sum_l gs[b,l]*x[b,l,:] --------------------------------------

__global__ __launch_bounds__(256) void pooled_partial_k(const float* __restrict__ x,
                                                        const float* __restrict__ gs,
                                                        float* __restrict__ pp) {
  int lc = blockIdx.x, b = blockIdx.y, d = threadIdx.x;
  const float* xp = x + ((long)b * LSEQ + lc * 256) * DM + d;
  const float* gp = gs + (long)b * LSEQ + lc * 256;
  float a = 0.f;
#pragma unroll 8
  for (int i = 0; i < 256; ++i) a = fmaf(gp[i], xp[(long)i * DM], a);
  pp[((long)lc * NB + b) * DM + d] = a;
}

__global__ __launch_bounds__(256) void pooled_reduce_k(const float* __restrict__ pp,
                                                       float* __restrict__ pooled) {
  int idx = blockIdx.x * 256 + threadIdx.x;  // < 8192
  int b = idx >> 8, d = idx & 255;
  float a = 0.f;
#pragma unroll
  for (int lc = 0; lc < 8; ++lc) a += pp[((long)lc * NB + b) * DM + d];
  pooled[idx] = a;
}

// ---- dense = relu([tm, pooled] @ dw + db) ---------------------------------

__global__ __launch_bounds__(256) void dense_k(const float* __restrict__ tm,
                                               const float* __restrict__ pooled,
                                               const float* __restrict__ dw,
                                               const float* __restrict__ db,
                                               float* __restrict__ dense) {
  __shared__ float f[2 * DM];
  int b = blockIdx.x, t = threadIdx.x;
  f[t] = tm[b * DM + t];
  f[DM + t] = pooled[b * DM + t];
  __syncthreads();
  float a = db[t];
#pragma unroll 8
  for (int k = 0; k < 2 * DM; ++k) a = fmaf(f[k], dw[(long)k * DM + t], a);
  dense[b * DM + t] = fmaxf(a, 0.f);
}

// ---- logits = dense @ pw + pb ---------------------------------------------

__global__ __launch_bounds__(256) void logits_k(const float* __restrict__ dense,
                                                const float* __restrict__ pw,
                                                const float* __restrict__ pb,
                                                float* __restrict__ logits, int C) {
  __shared__ float dS[DM];
  int b = blockIdx.y, t = threadIdx.x;
  int c = blockIdx.x * 256 + t;
  dS[t] = dense[b * DM + t];
  __syncthreads();
  if (c < C) {
    float a = pb[c];
#pragma unroll 8
    for (int k = 0; k < DM; ++k) a = fmaf(dS[k], pw[(long)k * C + c], a);
    logits[b * 1024 + c] = a;
  }
}

// ---- softmax over C, write pred, optionally w3 = pred/(C*Z) ---------------

__global__ __launch_bounds__(256) void softmax_k(const float* __restrict__ logits,
                                                 const float* __restrict__ Z,
                                                 float* __restrict__ out,
                                                 float* __restrict__ w,
                                                 int C, int writeW) {
  __shared__ float buf[1024];
  __shared__ float red[256];
  int b = blockIdx.x, t = threadIdx.x;
  float m = -1e30f;
  for (int c = t; c < C; c += 256) {
    float v = logits[b * 1024 + c];
    buf[c] = v;
    m = fmaxf(m, v);
  }
  red[t] = m;
  __syncthreads();
  for (int s2 = 128; s2 > 0; s2 >>= 1) {
    if (t < s2) red[t] = fmaxf(red[t], red[t + s2]);
    __syncthreads();
  }
  m = red[0];
  __syncthreads();
  float sum = 0.f;
  for (int c = t; c < C; c += 256) {
    float e = __expf(buf[c] - m);
    buf[c] = e;
    sum += e;
  }
  red[t] = sum;
  __syncthreads();
  for (int s2 = 128; s2 > 0; s2 >>= 1) {
    if (t < s2) red[t] += red[t + s2];
    __syncthreads();
  }
  float inv = 1.f / red[0];
  for (int c = t; c < C; c += 256) out[(long)b * C + c] = buf[c] * inv;
  if (writeW) {
    float invC = 1.f / (float)C;
    for (int c = t; c < 1024; c += 256)
      w[b * 1024 + c] = (c < C) ? (buf[c] * inv) * invC / Z[b * 1024 + c] : 0.f;
  }
}

// ---- host -----------------------------------------------------------------

extern "C" void kernel_launch(void* const* d_in, const int* in_sizes, int n_in,
                              void* d_out, int out_size, void* d_ws, size_t ws_size,
                              hipStream_t stream) {
  (void)in_sizes; (void)n_in; (void)out_size; (void)ws_size;
  const float* x = (const float*)d_in[0];

  const int Cs[3]     = {21, 191, 1009};
  const int ncts[3]   = {1, 2, 8};     // ceil(C/128)
  const int outoff[3] = {0, 672, 6784};

  float* ws = (float*)d_ws;
  float* sG     = ws; ws += 100 * RT;       // [100][RT] transposed scores-input
  float* ceG    = ws; ws += 3 * 102400;     // [3][100][1024] transposed, padded
  float* part   = ws; ws += 8 * NB * 1024;  // Z partials
  float* rowp   = ws; ws += 8 * RT;         // row-sum partials [ct][RT]
  float* Zb     = ws; ws += 32768;
  float* wb     = ws; ws += 32768;
  float* gs     = ws; ws += RT;
  float* prevb  = ws; ws += RT;
  float* tp     = ws; ws += 131072;
  float* tm     = ws; ws += 8192;
  float* pp     = ws; ws += 65536;
  float* pooled = ws; ws += 8192;
  float* dense  = ws; ws += 8192;
  float* logits = ws; ws += 32768;

  tm_partial_k<<<dim3(16, NB), 256, 0, stream>>>(x, tp);
  tm_reduce_k<<<32, 256, 0, stream>>>(tp, tm);
  for (int h = 0; h < 3; ++h)
    cet_k<<<400, 256, 0, stream>>>((const float*)d_in[1 + 6 * h], ceG + h * 102400, Cs[h]);

  for (int h = 0; h < 3; ++h) {
    const float* aw = (const float*)d_in[1 + 6 * h + 1];
    const float* dw = (const float*)d_in[1 + 6 * h + 2];
    const float* db = (const float*)d_in[1 + 6 * h + 3];
    const float* pw = (const float*)d_in[1 + 6 * h + 4];
    const float* pb = (const float*)d_in[1 + 6 * h + 5];
    const float* ceGh = ceG + h * 102400;
    const int C = Cs[h], nct = ncts[h];

    s_kernel<<<512, 256, 0, stream>>>(x, aw, prevb, sG, h > 0 ? 1 : 0);
    sweep_col<<<dim3(nct, 8, NB), 256, 0, stream>>>(sG, ceGh, part);
    wz_kernel<<<128, 256, 0, stream>>>(part, Zb, wb, C);
    sweep_row<<<dim3(8, NB, nct), 256, 0, stream>>>(sG, ceGh, wb, rowp);
    rowred_k<<<256, 256, 0, stream>>>(rowp, h > 0 ? prevb : nullptr, gs, nct);
    pooled_partial_k<<<dim3(8, NB), 256, 0, stream>>>(x, gs, pp);
    pooled_reduce_k<<<32, 256, 0, stream>>>(pp, pooled);
    dense_k<<<NB, 256, 0, stream>>>(tm, pooled, dw, db, dense);
    logits_k<<<dim3((C + 255) / 256, NB), 256, 0, stream>>>(dense, pw, pb, logits, C);
    softmax_k<<<NB, 256, 0, stream>>>(logits, Zb, (float*)d_out + outoff[h], wb, C, h < 2 ? 1 : 0);
    if (h < 2) {
      sweep_row<<<dim3(8, NB, nct), 256, 0, stream>>>(sG, ceGh, wb, rowp);
      rowred_k<<<256, 256, 0, stream>>>(rowp, nullptr, prevb, nct);
    }
  }
}

// Round 3
// 787.789 us; speedup vs baseline: 1.3636x; 1.1543x over previous
//
#include <hip/hip_runtime.h>
#include <math.h>

#define LSEQ 2048
#define NB   32
#define DM   256
#define RT   65536   // total rows B*L

typedef float f4 __attribute__((ext_vector_type(4)));
typedef __attribute__((ext_vector_type(4))) float f32x4;
typedef __attribute__((ext_vector_type(8))) short bf16x8;

// ---- bf16 helpers (bit-level, RNE) ----------------------------------------

__device__ __forceinline__ short f2bf(float f) {
  unsigned u = __float_as_uint(f);
  unsigned r = (u + 0x7fffu + ((u >> 16) & 1u)) >> 16;
  return (short)r;
}
__device__ __forceinline__ float bf2f(short s) {
  return __uint_as_float(((unsigned)(unsigned short)s) << 16);
}
__device__ __forceinline__ float tanh_fast(float z) {
  float e = __expf(2.f * z);
  return 1.f - __fdividef(2.f, 1.f + e);   // exact at +-inf, ~1e-6 rel otherwise
}

// ---- text_mean -------------------------------------------------------------

__global__ __launch_bounds__(256) void tm_partial_k(const float* __restrict__ x,
                                                    float* __restrict__ tp) {
  int lc = blockIdx.x, b = blockIdx.y, d = threadIdx.x;
  const float* xp = x + ((long)b * LSEQ + lc * 128) * DM + d;
  float a = 0.f;
#pragma unroll 8
  for (int i = 0; i < 128; ++i) a += xp[(long)i * DM];
  tp[((long)lc * NB + b) * DM + d] = a;
}

__global__ __launch_bounds__(256) void tm_reduce_k(const float* __restrict__ tp,
                                                   float* __restrict__ tm) {
  int idx = blockIdx.x * 256 + threadIdx.x;   // < 8192
  int b = idx >> 8, d = idx & 255;
  float a = 0.f;
#pragma unroll
  for (int lc = 0; lc < 16; ++lc) a += tp[((long)lc * NB + b) * DM + d];
  tm[idx] = a * (1.f / LSEQ);
}

// ---- weight conversions to split-bf16 -------------------------------------
// ceG: [1024 c][128 k] zero-padded, k-contiguous (B-operand layout)

__global__ __launch_bounds__(256) void cvt_ce(const float* __restrict__ ce,
                                              short* __restrict__ h,
                                              short* __restrict__ l, int C) {
  int idx = blockIdx.x * 256 + threadIdx.x;   // < 131072
  int c = idx >> 7, k = idx & 127;
  float v = (c < C && k < 100) ? ce[c * 100 + k] : 0.f;
  short hh = f2bf(v);
  h[idx] = hh;
  l[idx] = f2bf(v - bf2f(hh));
}

// awT: [128 e][256 k] zero-padded (transposed), k-contiguous

__global__ __launch_bounds__(256) void cvt_aw(const float* __restrict__ aw,
                                              short* __restrict__ h,
                                              short* __restrict__ l) {
  int idx = blockIdx.x * 256 + threadIdx.x;   // < 32768
  int e = idx >> 8, k = idx & 255;
  float v = (e < 100) ? aw[k * 100 + e] : 0.f;
  short hh = f2bf(v);
  h[idx] = hh;
  l[idx] = f2bf(v - bf2f(hh));
}

// ---- s_mfma: sG[r][e] = split_bf16(tanh(prev[r] * (x @ aw)[r][e])) --------
// grid 512 (row tiles of 128), 4 waves, wave tile 32 rows x 128 e, K=256

__global__ __launch_bounds__(256) void s_mfma(const float* __restrict__ x,
                                              const short* __restrict__ awh,
                                              const short* __restrict__ awl,
                                              const float* __restrict__ prevb,
                                              short* __restrict__ sGh,
                                              short* __restrict__ sGl, int hasPrev) {
  const int tid = threadIdx.x, lane = tid & 63, wv = tid >> 6;
  const int lo = lane & 15, hi = lane >> 4;
  const long r0 = (long)blockIdx.x * 128 + wv * 32;

  f32x4 acc[2][8];
#pragma unroll
  for (int m = 0; m < 2; ++m)
#pragma unroll
    for (int n = 0; n < 8; ++n) acc[m][n] = (f32x4){0.f, 0.f, 0.f, 0.f};

#pragma unroll 1
  for (int ks = 0; ks < 8; ++ks) {
    bf16x8 Ah[2], Al[2];
#pragma unroll
    for (int m = 0; m < 2; ++m) {
      const float* xp = x + (r0 + m * 16 + lo) * DM + ks * 32 + hi * 8;
      f4 v0 = *(const f4*)xp, v1 = *(const f4*)(xp + 4);
      float vv[8] = {v0[0], v0[1], v0[2], v0[3], v1[0], v1[1], v1[2], v1[3]};
#pragma unroll
      for (int i = 0; i < 8; ++i) {
        short hh = f2bf(vv[i]);
        Ah[m][i] = hh;
        Al[m][i] = f2bf(vv[i] - bf2f(hh));
      }
    }
#pragma unroll
    for (int n = 0; n < 8; ++n) {
      long boff = (long)(n * 16 + lo) * DM + ks * 32 + hi * 8;
      bf16x8 Bh = *(const bf16x8*)(awh + boff);
      bf16x8 Bl = *(const bf16x8*)(awl + boff);
#pragma unroll
      for (int m = 0; m < 2; ++m) {
        acc[m][n] = __builtin_amdgcn_mfma_f32_16x16x32_bf16(Ah[m], Bh, acc[m][n], 0, 0, 0);
        acc[m][n] = __builtin_amdgcn_mfma_f32_16x16x32_bf16(Ah[m], Bl, acc[m][n], 0, 0, 0);
        acc[m][n] = __builtin_amdgcn_mfma_f32_16x16x32_bf16(Al[m], Bh, acc[m][n], 0, 0, 0);
      }
    }
  }

  float pv[2][4];
#pragma unroll
  for (int m = 0; m < 2; ++m)
#pragma unroll
    for (int q = 0; q < 4; ++q) {
      long r = r0 + m * 16 + hi * 4 + q;
      pv[m][q] = hasPrev ? prevb[r] : 1.f;
    }
#pragma unroll
  for (int m = 0; m < 2; ++m)
#pragma unroll
    for (int n = 0; n < 8; ++n)
#pragma unroll
      for (int q = 0; q < 4; ++q) {
        long r = r0 + m * 16 + hi * 4 + q;
        float t = tanh_fast(pv[m][q] * acc[m][n][q]);
        short hh = f2bf(t);
        sGh[r * 128 + n * 16 + lo] = hh;
        sGl[r * 128 + n * 16 + lo] = f2bf(t - bf2f(hh));
      }
}

// ---- shared GEMM tile: acc[2][8] = S_tile(32r x 128k) @ ceT_tile(128k x 128c)
// 3-product split-bf16, K padded to 128

__device__ __forceinline__ void gemm_tile(const bf16x8 (&Ah)[2][4], const bf16x8 (&Al)[2][4],
                                          const short* __restrict__ ceh,
                                          const short* __restrict__ cel,
                                          int c0, int lo, int hi, f32x4 (&acc)[2][8]) {
#pragma unroll
  for (int m = 0; m < 2; ++m)
#pragma unroll
    for (int n = 0; n < 8; ++n) acc[m][n] = (f32x4){0.f, 0.f, 0.f, 0.f};
#pragma unroll
  for (int ks = 0; ks < 4; ++ks) {
#pragma unroll
    for (int n = 0; n < 8; ++n) {
      long boff = (long)(c0 + n * 16 + lo) * 128 + ks * 32 + hi * 8;
      bf16x8 Bh = *(const bf16x8*)(ceh + boff);
      bf16x8 Bl = *(const bf16x8*)(cel + boff);
#pragma unroll
      for (int m = 0; m < 2; ++m) {
        acc[m][n] = __builtin_amdgcn_mfma_f32_16x16x32_bf16(Ah[m][ks], Bh, acc[m][n], 0, 0, 0);
        acc[m][n] = __builtin_amdgcn_mfma_f32_16x16x32_bf16(Ah[m][ks], Bl, acc[m][n], 0, 0, 0);
        acc[m][n] = __builtin_amdgcn_mfma_f32_16x16x32_bf16(Al[m][ks], Bh, acc[m][n], 0, 0, 0);
      }
    }
  }
}

__device__ __forceinline__ void load_afrags(const short* __restrict__ sGh,
                                            const short* __restrict__ sGl,
                                            long r0, int lo, int hi,
                                            bf16x8 (&Ah)[2][4], bf16x8 (&Al)[2][4]) {
#pragma unroll
  for (int m = 0; m < 2; ++m)
#pragma unroll
    for (int ks = 0; ks < 4; ++ks) {
      long off = (r0 + m * 16 + lo) * 128 + ks * 32 + hi * 8;
      Ah[m][ks] = *(const bf16x8*)(sGh + off);
      Al[m][ks] = *(const bf16x8*)(sGl + off);
    }
}

// ---- mfma_col: colsum of exp(score) per 128-row chunk. grid 512 -----------

__global__ __launch_bounds__(256) void mfma_col(const short* __restrict__ sGh,
                                                const short* __restrict__ sGl,
                                                const short* __restrict__ ceh,
                                                const short* __restrict__ cel,
                                                float* __restrict__ partial, int nct) {
  __shared__ float lds[512];
  const int tid = threadIdx.x, lane = tid & 63, wv = tid >> 6;
  const int lo = lane & 15, hi = lane >> 4;
  const long r0 = (long)blockIdx.x * 128 + wv * 32;

  bf16x8 Ah[2][4], Al[2][4];
  load_afrags(sGh, sGl, r0, lo, hi, Ah, Al);

#pragma unroll 1
  for (int ct = 0; ct < nct; ++ct) {
    f32x4 acc[2][8];
    gemm_tile(Ah, Al, ceh, cel, ct * 128, lo, hi, acc);
#pragma unroll
    for (int n = 0; n < 8; ++n) {
      float s = 0.f;
#pragma unroll
      for (int m = 0; m < 2; ++m)
#pragma unroll
        for (int q = 0; q < 4; ++q) s += __expf(acc[m][n][q]);
      s += __shfl_xor(s, 16);
      s += __shfl_xor(s, 32);
      if (lane < 16) lds[wv * 128 + n * 16 + lane] = s;
    }
    __syncthreads();
    if (tid < 128)
      partial[(long)blockIdx.x * 1024 + ct * 128 + tid] =
          lds[tid] + lds[128 + tid] + lds[256 + tid] + lds[384 + tid];
    __syncthreads();
  }
}

// ---- wz: Z = sum of 16 chunk partials per batch; w = 1/(C*Z) --------------

__global__ __launch_bounds__(256) void wz_kernel(const float* __restrict__ partial,
                                                 float* __restrict__ Z,
                                                 float* __restrict__ w, int C) {
  int idx = blockIdx.x * 256 + threadIdx.x;  // < 32768
  int b = idx >> 10, c = idx & 1023;
  float z = 0.f;
#pragma unroll
  for (int i = 0; i < 16; ++i) z += partial[(long)(b * 16 + i) * 1024 + c];
  Z[idx] = z;
  w[idx] = (c < C) ? 1.f / ((float)C * z) : 0.f;
}

// ---- mfma_row: out[r] = (ps[r]?) * sum_c exp(score[r][c]) * w[c] ----------

__global__ __launch_bounds__(256) void mfma_row(const short* __restrict__ sGh,
                                                const short* __restrict__ sGl,
                                                const short* __restrict__ ceh,
                                                const short* __restrict__ cel,
                                                const float* __restrict__ w,
                                                const float* __restrict__ ps,
                                                float* __restrict__ out, int nct) {
  const int tid = threadIdx.x, lane = tid & 63, wv = tid >> 6;
  const int lo = lane & 15, hi = lane >> 4;
  const long r0 = (long)blockIdx.x * 128 + wv * 32;
  const int b = blockIdx.x >> 4;

  bf16x8 Ah[2][4], Al[2][4];
  load_afrags(sGh, sGl, r0, lo, hi, Ah, Al);

  float racc[2][4];
#pragma unroll
  for (int m = 0; m < 2; ++m)
#pragma unroll
    for (int q = 0; q < 4; ++q) racc[m][q] = 0.f;

#pragma unroll 1
  for (int ct = 0; ct < nct; ++ct) {
    f32x4 acc[2][8];
    gemm_tile(Ah, Al, ceh, cel, ct * 128, lo, hi, acc);
#pragma unroll
    for (int n = 0; n < 8; ++n) {
      float wj = w[b * 1024 + ct * 128 + n * 16 + lo];
#pragma unroll
      for (int m = 0; m < 2; ++m)
#pragma unroll
        for (int q = 0; q < 4; ++q)
          racc[m][q] = fmaf(__expf(acc[m][n][q]), wj, racc[m][q]);
    }
  }

#pragma unroll
  for (int m = 0; m < 2; ++m)
#pragma unroll
    for (int q = 0; q < 4; ++q) {
      float v = racc[m][q];
      v += __shfl_xor(v, 1);
      v += __shfl_xor(v, 2);
      v += __shfl_xor(v, 4);
      v += __shfl_xor(v, 8);
      if (lo == 0) {
        long r = r0 + m * 16 + hi * 4 + q;
        out[r] = ps ? v * ps[r] : v;
      }
    }
}

// ---- pooled = sum_l gs[b,l]*x[b,l,:] --------------------------------------

__global__ __launch_bounds__(256) void pooled_partial_k(const float* __restrict__ x,
                                                        const float* __restrict__ gs,
                                                        float* __restrict__ pp) {
  int lc = blockIdx.x, b = blockIdx.y, d = threadIdx.x;
  const float* xp = x + ((long)b * LSEQ + lc * 256) * DM + d;
  const float* gp = gs + (long)b * LSEQ + lc * 256;
  float a = 0.f;
#pragma unroll 8
  for (int i = 0; i < 256; ++i) a = fmaf(gp[i], xp[(long)i * DM], a);
  pp[((long)lc * NB + b) * DM + d] = a;
}

__global__ __launch_bounds__(256) void pooled_reduce_k(const float* __restrict__ pp,
                                                       float* __restrict__ pooled) {
  int idx = blockIdx.x * 256 + threadIdx.x;  // < 8192
  int b = idx >> 8, d = idx & 255;
  float a = 0.f;
#pragma unroll
  for (int lc = 0; lc < 8; ++lc) a += pp[((long)lc * NB + b) * DM + d];
  pooled[idx] = a;
}

// ---- dense = relu([tm, pooled] @ dw + db) ---------------------------------

__global__ __launch_bounds__(256) void dense_k(const float* __restrict__ tm,
                                               const float* __restrict__ pooled,
                                               const float* __restrict__ dw,
                                               const float* __restrict__ db,
                                               float* __restrict__ dense) {
  __shared__ float f[2 * DM];
  int b = blockIdx.x, t = threadIdx.x;
  f[t] = tm[b * DM + t];
  f[DM + t] = pooled[b * DM + t];
  __syncthreads();
  float a = db[t];
#pragma unroll 8
  for (int k = 0; k < 2 * DM; ++k) a = fmaf(f[k], dw[(long)k * DM + t], a);
  dense[b * DM + t] = fmaxf(a, 0.f);
}

// ---- logits = dense @ pw + pb ---------------------------------------------

__global__ __launch_bounds__(256) void logits_k(const float* __restrict__ dense,
                                                const float* __restrict__ pw,
                                                const float* __restrict__ pb,
                                                float* __restrict__ logits, int C) {
  __shared__ float dS[DM];
  int b = blockIdx.y, t = threadIdx.x;
  int c = blockIdx.x * 256 + t;
  dS[t] = dense[b * DM + t];
  __syncthreads();
  if (c < C) {
    float a = pb[c];
#pragma unroll 8
    for (int k = 0; k < DM; ++k) a = fmaf(dS[k], pw[(long)k * C + c], a);
    logits[b * 1024 + c] = a;
  }
}

// ---- softmax over C, write pred, optionally w3 = pred/(C*Z) ---------------

__global__ __launch_bounds__(256) void softmax_k(const float* __restrict__ logits,
                                                 const float* __restrict__ Z,
                                                 float* __restrict__ out,
                                                 float* __restrict__ w,
                                                 int C, int writeW) {
  __shared__ float buf[1024];
  __shared__ float red[256];
  int b = blockIdx.x, t = threadIdx.x;
  float m = -1e30f;
  for (int c = t; c < C; c += 256) {
    float v = logits[b * 1024 + c];
    buf[c] = v;
    m = fmaxf(m, v);
  }
  red[t] = m;
  __syncthreads();
  for (int s2 = 128; s2 > 0; s2 >>= 1) {
    if (t < s2) red[t] = fmaxf(red[t], red[t + s2]);
    __syncthreads();
  }
  m = red[0];
  __syncthreads();
  float sum = 0.f;
  for (int c = t; c < C; c += 256) {
    float e = __expf(buf[c] - m);
    buf[c] = e;
    sum += e;
  }
  red[t] = sum;
  __syncthreads();
  for (int s2 = 128; s2 > 0; s2 >>= 1) {
    if (t < s2) red[t] += red[t + s2];
    __syncthreads();
  }
  float inv = 1.f / red[0];
  for (int c = t; c < C; c += 256) out[(long)b * C + c] = buf[c] * inv;
  if (writeW) {
    float invC = 1.f / (float)C;
    for (int c = t; c < 1024; c += 256)
      w[b * 1024 + c] = (c < C) ? (buf[c] * inv) * invC / Z[b * 1024 + c] : 0.f;
  }
}

// ---- host -----------------------------------------------------------------

extern "C" void kernel_launch(void* const* d_in, const int* in_sizes, int n_in,
                              void* d_out, int out_size, void* d_ws, size_t ws_size,
                              hipStream_t stream) {
  (void)in_sizes; (void)n_in; (void)out_size; (void)ws_size;
  const float* x = (const float*)d_in[0];

  const int Cs[3]     = {21, 191, 1009};
  const int ncts[3]   = {1, 2, 8};
  const int outoff[3] = {0, 672, 6784};

  char* base = (char*)d_ws;
  short* sGh = (short*)base; base += (size_t)RT * 128 * 2;
  short* sGl = (short*)base; base += (size_t)RT * 128 * 2;
  short* ceh = (short*)base; base += (size_t)3 * 131072 * 2;
  short* cel = (short*)base; base += (size_t)3 * 131072 * 2;
  short* awh = (short*)base; base += (size_t)3 * 32768 * 2;
  short* awl = (short*)base; base += (size_t)3 * 32768 * 2;
  float* partial = (float*)base; base += (size_t)512 * 1024 * 4;
  float* Zb     = (float*)base; base += 32768 * 4;
  float* wb     = (float*)base; base += 32768 * 4;
  float* gs     = (float*)base; base += RT * 4;
  float* prevb  = (float*)base; base += RT * 4;
  float* tp     = (float*)base; base += 131072 * 4;
  float* tm     = (float*)base; base += 8192 * 4;
  float* pp     = (float*)base; base += 65536 * 4;
  float* pooled = (float*)base; base += 8192 * 4;
  float* dense  = (float*)base; base += 8192 * 4;
  float* logits = (float*)base; base += 32768 * 4;

  tm_partial_k<<<dim3(16, NB), 256, 0, stream>>>(x, tp);
  tm_reduce_k<<<32, 256, 0, stream>>>(tp, tm);
  for (int h = 0; h < 3; ++h) {
    cvt_ce<<<512, 256, 0, stream>>>((const float*)d_in[1 + 6 * h], ceh + h * 131072,
                                    cel + h * 131072, Cs[h]);
    cvt_aw<<<128, 256, 0, stream>>>((const float*)d_in[1 + 6 * h + 1], awh + h * 32768,
                                    awl + h * 32768);
  }

  for (int h = 0; h < 3; ++h) {
    const float* dw = (const float*)d_in[1 + 6 * h + 2];
    const float* db = (const float*)d_in[1 + 6 * h + 3];
    const float* pw = (const float*)d_in[1 + 6 * h + 4];
    const float* pb = (const float*)d_in[1 + 6 * h + 5];
    const short* ch = ceh + h * 131072;
    const short* cl = cel + h * 131072;
    const int C = Cs[h], nct = ncts[h];

    s_mfma<<<512, 256, 0, stream>>>(x, awh + h * 32768, awl + h * 32768, prevb, sGh, sGl,
                                    h > 0 ? 1 : 0);
    mfma_col<<<512, 256, 0, stream>>>(sGh, sGl, ch, cl, partial, nct);
    wz_kernel<<<128, 256, 0, stream>>>(partial, Zb, wb, C);
    mfma_row<<<512, 256, 0, stream>>>(sGh, sGl, ch, cl, wb, h > 0 ? prevb : nullptr, gs, nct);
    pooled_partial_k<<<dim3(8, NB), 256, 0, stream>>>(x, gs, pp);
    pooled_reduce_k<<<32, 256, 0, stream>>>(pp, pooled);
    dense_k<<<NB, 256, 0, stream>>>(tm, pooled, dw, db, dense);
    logits_k<<<dim3((C + 255) / 256, NB), 256, 0, stream>>>(dense, pw, pb, logits, C);
    softmax_k<<<NB, 256, 0, stream>>>(logits, Zb, (float*)d_out + outoff[h], wb, C,
                                      h < 2 ? 1 : 0);
    if (h < 2)
      mfma_row<<<512, 256, 0, stream>>>(sGh, sGl, ch, cl, wb, nullptr, prevb, nct);
  }
}

// Round 4
// 711.901 us; speedup vs baseline: 1.5090x; 1.1066x over previous
//
#include <hip/hip_runtime.h>
#include <math.h>

#define LSEQ 2048
#define NB   32
#define DM   256
#define RT   65536   // total rows B*L

typedef float f4 __attribute__((ext_vector_type(4)));
typedef __attribute__((ext_vector_type(4))) float f32x4;
typedef __attribute__((ext_vector_type(8))) short bf16x8;

#define MFMA16 __builtin_amdgcn_mfma_f32_16x16x32_bf16

// ---- bf16 helpers (bit-level, RNE) ----------------------------------------

__device__ __forceinline__ short f2bf(float f) {
  unsigned u = __float_as_uint(f);
  unsigned r = (u + 0x7fffu + ((u >> 16) & 1u)) >> 16;
  return (short)r;
}
__device__ __forceinline__ float bf2f(short s) {
  return __uint_as_float(((unsigned)(unsigned short)s) << 16);
}
__device__ __forceinline__ float tanh_fast(float z) {
  float e = __expf(2.f * z);
  return 1.f - __fdividef(2.f, 1.f + e);
}

// ---- x -> split bf16 (once) -----------------------------------------------

__global__ __launch_bounds__(256) void cvt_x(const float* __restrict__ x,
                                             short* __restrict__ xh,
                                             short* __restrict__ xl) {
  long idx = ((long)blockIdx.x * 256 + threadIdx.x) * 8;   // over RT*256
  f4 v0 = *(const f4*)(x + idx), v1 = *(const f4*)(x + idx + 4);
  float vv[8] = {v0[0], v0[1], v0[2], v0[3], v1[0], v1[1], v1[2], v1[3]};
  bf16x8 h, l;
#pragma unroll
  for (int i = 0; i < 8; ++i) {
    short hh = f2bf(vv[i]);
    h[i] = hh;
    l[i] = f2bf(vv[i] - bf2f(hh));
  }
  *(bf16x8*)(xh + idx) = h;
  *(bf16x8*)(xl + idx) = l;
}

// ---- text_mean -------------------------------------------------------------

__global__ __launch_bounds__(256) void tm_partial_k(const float* __restrict__ x,
                                                    float* __restrict__ tp) {
  int lc = blockIdx.x, b = blockIdx.y, d = threadIdx.x;
  const float* xp = x + ((long)b * LSEQ + lc * 128) * DM + d;
  float a = 0.f;
#pragma unroll 8
  for (int i = 0; i < 128; ++i) a += xp[(long)i * DM];
  tp[((long)lc * NB + b) * DM + d] = a;
}

__global__ __launch_bounds__(256) void tm_reduce_k(const float* __restrict__ tp,
                                                   float* __restrict__ tm) {
  int idx = blockIdx.x * 256 + threadIdx.x;   // < 8192
  int b = idx >> 8, d = idx & 255;
  float a = 0.f;
#pragma unroll
  for (int lc = 0; lc < 16; ++lc) a += tp[((long)lc * NB + b) * DM + d];
  tm[idx] = a * (1.f / LSEQ);
}

// ---- weight conversions to split-bf16 -------------------------------------

__global__ __launch_bounds__(256) void cvt_ce(const float* __restrict__ ce,
                                              short* __restrict__ h,
                                              short* __restrict__ l, int C) {
  int idx = blockIdx.x * 256 + threadIdx.x;   // < 131072, [c][128k]
  int c = idx >> 7, k = idx & 127;
  float v = (c < C && k < 100) ? ce[c * 100 + k] : 0.f;
  short hh = f2bf(v);
  h[idx] = hh;
  l[idx] = f2bf(v - bf2f(hh));
}

__global__ __launch_bounds__(256) void cvt_aw(const float* __restrict__ aw,
                                              short* __restrict__ h,
                                              short* __restrict__ l) {
  int idx = blockIdx.x * 256 + threadIdx.x;   // < 32768, [e][256k]
  int e = idx >> 8, k = idx & 255;
  float v = (e < 100) ? aw[k * 100 + e] : 0.f;
  short hh = f2bf(v);
  h[idx] = hh;
  l[idx] = f2bf(v - bf2f(hh));
}

// ---- s_mfma: sG[r][e] = split_bf16(tanh(prev[r] * (x @ aw)[r][e])) --------
// grid 512, 4 waves, wave = 32 rows; 2 strips of 64 e; K=256 in 2 halves

__global__ __launch_bounds__(256) void s_mfma(const short* __restrict__ xh,
                                              const short* __restrict__ xl,
                                              const short* __restrict__ awh,
                                              const short* __restrict__ awl,
                                              const float* __restrict__ prevb,
                                              short* __restrict__ sGh,
                                              short* __restrict__ sGl, int hasPrev) {
  const int tid = threadIdx.x, lane = tid & 63, wv = tid >> 6;
  const int lo = lane & 15, hi = lane >> 4;
  const long r0 = (long)blockIdx.x * 128 + wv * 32;

  float pv[2][4];
#pragma unroll
  for (int m = 0; m < 2; ++m)
#pragma unroll
    for (int q = 0; q < 4; ++q)
      pv[m][q] = hasPrev ? prevb[r0 + m * 16 + hi * 4 + q] : 1.f;

#pragma unroll 1
  for (int st = 0; st < 2; ++st) {
    f32x4 acc[2][4];
#pragma unroll
    for (int m = 0; m < 2; ++m)
#pragma unroll
      for (int n = 0; n < 4; ++n) acc[m][n] = (f32x4){0.f, 0.f, 0.f, 0.f};

    for (int kh = 0; kh < 2; ++kh) {
      bf16x8 Ah[2][4], Al[2][4];
#pragma unroll
      for (int m = 0; m < 2; ++m)
#pragma unroll
        for (int ks = 0; ks < 4; ++ks) {
          long off = (r0 + m * 16 + lo) * 256 + kh * 128 + ks * 32 + hi * 8;
          Ah[m][ks] = *(const bf16x8*)(xh + off);
          Al[m][ks] = *(const bf16x8*)(xl + off);
        }
      bf16x8 Bh[4][4], Bl[4][4];
#pragma unroll
      for (int n = 0; n < 4; ++n)
#pragma unroll
        for (int ks = 0; ks < 4; ++ks) {
          long boff = (long)(st * 64 + n * 16 + lo) * 256 + kh * 128 + ks * 32 + hi * 8;
          Bh[n][ks] = *(const bf16x8*)(awh + boff);
          Bl[n][ks] = *(const bf16x8*)(awl + boff);
        }
#pragma unroll
      for (int ks = 0; ks < 4; ++ks)
#pragma unroll
        for (int n = 0; n < 4; ++n)
#pragma unroll
          for (int m = 0; m < 2; ++m) {
            acc[m][n] = MFMA16(Ah[m][ks], Bh[n][ks], acc[m][n], 0, 0, 0);
            acc[m][n] = MFMA16(Al[m][ks], Bh[n][ks], acc[m][n], 0, 0, 0);
            acc[m][n] = MFMA16(Ah[m][ks], Bl[n][ks], acc[m][n], 0, 0, 0);
          }
    }

#pragma unroll
    for (int m = 0; m < 2; ++m)
#pragma unroll
      for (int n = 0; n < 4; ++n)
#pragma unroll
        for (int q = 0; q < 4; ++q) {
          long r = r0 + m * 16 + hi * 4 + q;
          int c = st * 64 + n * 16 + lo;
          float t = tanh_fast(pv[m][q] * acc[m][n][q]);
          short hh = f2bf(t);
          sGh[r * 128 + c] = hh;
          sGl[r * 128 + c] = f2bf(t - bf2f(hh));
        }
  }
}

// ---- sweep core: A-frags resident, B batched per 64-col strip -------------

__device__ __forceinline__ void load_afrags(const short* __restrict__ sGh,
                                            const short* __restrict__ sGl,
                                            long r0, int lo, int hi,
                                            bf16x8 (&Ah)[2][4], bf16x8 (&Al)[2][4]) {
#pragma unroll
  for (int m = 0; m < 2; ++m)
#pragma unroll
    for (int ks = 0; ks < 4; ++ks) {
      long off = (r0 + m * 16 + lo) * 128 + ks * 32 + hi * 8;
      Ah[m][ks] = *(const bf16x8*)(sGh + off);
      Al[m][ks] = *(const bf16x8*)(sGl + off);
    }
}

__device__ __forceinline__ void gemm_strip(const bf16x8 (&Ah)[2][4], const bf16x8 (&Al)[2][4],
                                           const short* __restrict__ ceh,
                                           const short* __restrict__ cel,
                                           int c0s, int lo, int hi, f32x4 (&acc)[2][4]) {
#pragma unroll
  for (int m = 0; m < 2; ++m)
#pragma unroll
    for (int n = 0; n < 4; ++n) acc[m][n] = (f32x4){0.f, 0.f, 0.f, 0.f};
  bf16x8 Bh[4][4], Bl[4][4];
#pragma unroll
  for (int n = 0; n < 4; ++n)
#pragma unroll
    for (int ks = 0; ks < 4; ++ks) {
      long boff = (long)(c0s + n * 16 + lo) * 128 + ks * 32 + hi * 8;
      Bh[n][ks] = *(const bf16x8*)(ceh + boff);
      Bl[n][ks] = *(const bf16x8*)(cel + boff);
    }
#pragma unroll
  for (int ks = 0; ks < 4; ++ks)
#pragma unroll
    for (int n = 0; n < 4; ++n)
#pragma unroll
      for (int m = 0; m < 2; ++m) {
        acc[m][n] = MFMA16(Ah[m][ks], Bh[n][ks], acc[m][n], 0, 0, 0);
        acc[m][n] = MFMA16(Al[m][ks], Bh[n][ks], acc[m][n], 0, 0, 0);
        acc[m][n] = MFMA16(Ah[m][ks], Bl[n][ks], acc[m][n], 0, 0, 0);
      }
}

// ---- mfma_col: per-wave column partials of exp(score). grid 512 -----------

__global__ __launch_bounds__(256) void mfma_col(const short* __restrict__ sGh,
                                                const short* __restrict__ sGl,
                                                const short* __restrict__ ceh,
                                                const short* __restrict__ cel,
                                                float* __restrict__ partial, int nstrips) {
  const int tid = threadIdx.x, lane = tid & 63, wv = tid >> 6;
  const int lo = lane & 15, hi = lane >> 4;
  const long r0 = (long)blockIdx.x * 128 + wv * 32;
  const long gw = (long)blockIdx.x * 4 + wv;

  bf16x8 Ah[2][4], Al[2][4];
  load_afrags(sGh, sGl, r0, lo, hi, Ah, Al);

#pragma unroll 1
  for (int st = 0; st < nstrips; ++st) {
    f32x4 acc[2][4];
    gemm_strip(Ah, Al, ceh, cel, st * 64, lo, hi, acc);
#pragma unroll
    for (int n = 0; n < 4; ++n) {
      float s = 0.f;
#pragma unroll
      for (int m = 0; m < 2; ++m)
#pragma unroll
        for (int q = 0; q < 4; ++q) s += __expf(acc[m][n][q]);
      s += __shfl_xor(s, 16);
      s += __shfl_xor(s, 32);
      if (lane < 16) partial[gw * 1024 + st * 64 + n * 16 + lane] = s;
    }
  }
}

// ---- wz: Z = sum of 64 wave partials per batch; w = 1/(C*Z) ---------------

__global__ __launch_bounds__(256) void wz_kernel(const float* __restrict__ partial,
                                                 float* __restrict__ Z,
                                                 float* __restrict__ w, int C) {
  int idx = blockIdx.x * 256 + threadIdx.x;  // < 32768
  int b = idx >> 10, c = idx & 1023;
  float z = 0.f;
#pragma unroll 8
  for (int i = 0; i < 64; ++i) z += partial[(long)(b * 64 + i) * 1024 + c];
  Z[idx] = z;
  w[idx] = (c < C) ? 1.f / ((float)C * z) : 0.f;
}

// ---- mfma_row: out[r] = (ps[r]?) * sum_c exp(score[r][c]) * w[c] ----------

__global__ __launch_bounds__(256) void mfma_row(const short* __restrict__ sGh,
                                                const short* __restrict__ sGl,
                                                const short* __restrict__ ceh,
                                                const short* __restrict__ cel,
                                                const float* __restrict__ w,
                                                const float* __restrict__ ps,
                                                float* __restrict__ out, int nstrips) {
  const int tid = threadIdx.x, lane = tid & 63, wv = tid >> 6;
  const int lo = lane & 15, hi = lane >> 4;
  const long r0 = (long)blockIdx.x * 128 + wv * 32;
  const int b = blockIdx.x >> 4;

  bf16x8 Ah[2][4], Al[2][4];
  load_afrags(sGh, sGl, r0, lo, hi, Ah, Al);

  float racc[2][4];
#pragma unroll
  for (int m = 0; m < 2; ++m)
#pragma unroll
    for (int q = 0; q < 4; ++q) racc[m][q] = 0.f;

#pragma unroll 1
  for (int st = 0; st < nstrips; ++st) {
    f32x4 acc[2][4];
    gemm_strip(Ah, Al, ceh, cel, st * 64, lo, hi, acc);
#pragma unroll
    for (int n = 0; n < 4; ++n) {
      float wj = w[b * 1024 + st * 64 + n * 16 + lo];
#pragma unroll
      for (int m = 0; m < 2; ++m)
#pragma unroll
        for (int q = 0; q < 4; ++q)
          racc[m][q] = fmaf(__expf(acc[m][n][q]), wj, racc[m][q]);
    }
  }

#pragma unroll
  for (int m = 0; m < 2; ++m)
#pragma unroll
    for (int q = 0; q < 4; ++q) {
      float v = racc[m][q];
      v += __shfl_xor(v, 1);
      v += __shfl_xor(v, 2);
      v += __shfl_xor(v, 4);
      v += __shfl_xor(v, 8);
      if (lo == 0) {
        long r = r0 + m * 16 + hi * 4 + q;
        out[r] = ps ? v * ps[r] : v;
      }
    }
}

// ---- pooled = sum_l gs[b,l]*x[b,l,:]  (x as bf16-hi) ----------------------

__global__ __launch_bounds__(256) void pooled_partial_k(const short* __restrict__ xh,
                                                        const float* __restrict__ gs,
                                                        float* __restrict__ pp) {
  int lc = blockIdx.x, b = blockIdx.y, d = threadIdx.x;
  const short* xp = xh + ((long)b * LSEQ + lc * 256) * DM + d;
  const float* gp = gs + (long)b * LSEQ + lc * 256;
  float a = 0.f;
#pragma unroll 8
  for (int i = 0; i < 256; ++i) a = fmaf(gp[i], bf2f(xp[(long)i * DM]), a);
  pp[((long)lc * NB + b) * DM + d] = a;
}

__global__ __launch_bounds__(256) void pooled_reduce_k(const float* __restrict__ pp,
                                                       float* __restrict__ pooled) {
  int idx = blockIdx.x * 256 + threadIdx.x;  // < 8192
  int b = idx >> 8, d = idx & 255;
  float a = 0.f;
#pragma unroll
  for (int lc = 0; lc < 8; ++lc) a += pp[((long)lc * NB + b) * DM + d];
  pooled[idx] = a;
}

// ---- dense = relu([tm, pooled] @ dw + db) ---------------------------------

__global__ __launch_bounds__(256) void dense_k(const float* __restrict__ tm,
                                               const float* __restrict__ pooled,
                                               const float* __restrict__ dw,
                                               const float* __restrict__ db,
                                               float* __restrict__ dense) {
  __shared__ float f[2 * DM];
  int b = blockIdx.x, t = threadIdx.x;
  f[t] = tm[b * DM + t];
  f[DM + t] = pooled[b * DM + t];
  __syncthreads();
  float a = db[t];
#pragma unroll 8
  for (int k = 0; k < 2 * DM; ++k) a = fmaf(f[k], dw[(long)k * DM + t], a);
  dense[b * DM + t] = fmaxf(a, 0.f);
}

// ---- logits = dense @ pw + pb ---------------------------------------------

__global__ __launch_bounds__(256) void logits_k(const float* __restrict__ dense,
                                                const float* __restrict__ pw,
                                                const float* __restrict__ pb,
                                                float* __restrict__ logits, int C) {
  __shared__ float dS[DM];
  int b = blockIdx.y, t = threadIdx.x;
  int c = blockIdx.x * 256 + t;
  dS[t] = dense[b * DM + t];
  __syncthreads();
  if (c < C) {
    float a = pb[c];
#pragma unroll 8
    for (int k = 0; k < DM; ++k) a = fmaf(dS[k], pw[(long)k * C + c], a);
    logits[b * 1024 + c] = a;
  }
}

// ---- softmax over C, write pred, optionally w3 = pred/(C*Z) ---------------

__global__ __launch_bounds__(256) void softmax_k(const float* __restrict__ logits,
                                                 const float* __restrict__ Z,
                                                 float* __restrict__ out,
                                                 float* __restrict__ w,
                                                 int C, int writeW) {
  __shared__ float buf[1024];
  __shared__ float red[256];
  int b = blockIdx.x, t = threadIdx.x;
  float m = -1e30f;
  for (int c = t; c < C; c += 256) {
    float v = logits[b * 1024 + c];
    buf[c] = v;
    m = fmaxf(m, v);
  }
  red[t] = m;
  __syncthreads();
  for (int s2 = 128; s2 > 0; s2 >>= 1) {
    if (t < s2) red[t] = fmaxf(red[t], red[t + s2]);
    __syncthreads();
  }
  m = red[0];
  __syncthreads();
  float sum = 0.f;
  for (int c = t; c < C; c += 256) {
    float e = __expf(buf[c] - m);
    buf[c] = e;
    sum += e;
  }
  red[t] = sum;
  __syncthreads();
  for (int s2 = 128; s2 > 0; s2 >>= 1) {
    if (t < s2) red[t] += red[t + s2];
    __syncthreads();
  }
  float inv = 1.f / red[0];
  for (int c = t; c < C; c += 256) out[(long)b * C + c] = buf[c] * inv;
  if (writeW) {
    float invC = 1.f / (float)C;
    for (int c = t; c < 1024; c += 256)
      w[b * 1024 + c] = (c < C) ? (buf[c] * inv) * invC / Z[b * 1024 + c] : 0.f;
  }
}

// ---- host -----------------------------------------------------------------

extern "C" void kernel_launch(void* const* d_in, const int* in_sizes, int n_in,
                              void* d_out, int out_size, void* d_ws, size_t ws_size,
                              hipStream_t stream) {
  (void)in_sizes; (void)n_in; (void)out_size; (void)ws_size;
  const float* x = (const float*)d_in[0];

  const int Cs[3]      = {21, 191, 1009};
  const int nstrips[3] = {1, 3, 16};   // ceil(C/64)
  const int outoff[3]  = {0, 672, 6784};

  char* base = (char*)d_ws;
  short* xh  = (short*)base; base += (size_t)RT * 256 * 2;
  short* xl  = (short*)base; base += (size_t)RT * 256 * 2;
  short* sGh = (short*)base; base += (size_t)RT * 128 * 2;
  short* sGl = (short*)base; base += (size_t)RT * 128 * 2;
  short* ceh = (short*)base; base += (size_t)3 * 131072 * 2;
  short* cel = (short*)base; base += (size_t)3 * 131072 * 2;
  short* awh = (short*)base; base += (size_t)3 * 32768 * 2;
  short* awl = (short*)base; base += (size_t)3 * 32768 * 2;
  float* partial = (float*)base; base += (size_t)2048 * 1024 * 4;
  float* Zb     = (float*)base; base += 32768 * 4;
  float* wb     = (float*)base; base += 32768 * 4;
  float* gs     = (float*)base; base += RT * 4;
  float* prevb  = (float*)base; base += RT * 4;
  float* tp     = (float*)base; base += 131072 * 4;
  float* tm     = (float*)base; base += 8192 * 4;
  float* pp     = (float*)base; base += 65536 * 4;
  float* pooled = (float*)base; base += 8192 * 4;
  float* dense  = (float*)base; base += 8192 * 4;
  float* logits = (float*)base; base += 32768 * 4;

  cvt_x<<<8192, 256, 0, stream>>>(x, xh, xl);
  tm_partial_k<<<dim3(16, NB), 256, 0, stream>>>(x, tp);
  tm_reduce_k<<<32, 256, 0, stream>>>(tp, tm);
  for (int h = 0; h < 3; ++h) {
    cvt_ce<<<512, 256, 0, stream>>>((const float*)d_in[1 + 6 * h], ceh + h * 131072,
                                    cel + h * 131072, Cs[h]);
    cvt_aw<<<128, 256, 0, stream>>>((const float*)d_in[1 + 6 * h + 1], awh + h * 32768,
                                    awl + h * 32768);
  }

  for (int h = 0; h < 3; ++h) {
    const float* dw = (const float*)d_in[1 + 6 * h + 2];
    const float* db = (const float*)d_in[1 + 6 * h + 3];
    const float* pw = (const float*)d_in[1 + 6 * h + 4];
    const float* pb = (const float*)d_in[1 + 6 * h + 5];
    const short* ch = ceh + h * 131072;
    const short* cl = cel + h * 131072;
    const int C = Cs[h], ns = nstrips[h];

    s_mfma<<<512, 256, 0, stream>>>(xh, xl, awh + h * 32768, awl + h * 32768, prevb,
                                    sGh, sGl, h > 0 ? 1 : 0);
    mfma_col<<<512, 256, 0, stream>>>(sGh, sGl, ch, cl, partial, ns);
    wz_kernel<<<128, 256, 0, stream>>>(partial, Zb, wb, C);
    mfma_row<<<512, 256, 0, stream>>>(sGh, sGl, ch, cl, wb, h > 0 ? prevb : nullptr, gs, ns);
    pooled_partial_k<<<dim3(8, NB), 256, 0, stream>>>(xh, gs, pp);
    pooled_reduce_k<<<32, 256, 0, stream>>>(pp, pooled);
    dense_k<<<NB, 256, 0, stream>>>(tm, pooled, dw, db, dense);
    logits_k<<<dim3((C + 255) / 256, NB), 256, 0, stream>>>(dense, pw, pb, logits, C);
    softmax_k<<<NB, 256, 0, stream>>>(logits, Zb, (float*)d_out + outoff[h], wb, C,
                                      h < 2 ? 1 : 0);
    if (h < 2)
      mfma_row<<<512, 256, 0, stream>>>(sGh, sGl, ch, cl, wb, nullptr, prevb, ns);
  }
}